// Round 1
// baseline (4703.910 us; speedup 1.0000x reference)
//
#include <hip/hip_runtime.h>

typedef __bf16 bf16_t;
typedef __bf16 bf16x8 __attribute__((ext_vector_type(8)));
typedef float f32x4 __attribute__((ext_vector_type(4)));
typedef unsigned int u32;

#define SEQ    1024
#define DEMB   1024
#define NHEAD  16
#define DVDIM  64
#define DMLP   4096
#define NVOCAB 32000
#define NLAYER 4

union FragU { u32 u[4]; bf16x8 v; };
union PackU { bf16_t h[2]; u32 u; };

// ---------------------------------------------------------------- reductions
__device__ __forceinline__ float blockSum(float v, float* red) {
  #pragma unroll
  for (int o = 32; o > 0; o >>= 1) v += __shfl_down(v, o, 64);
  __syncthreads();
  if ((threadIdx.x & 63) == 0) red[threadIdx.x >> 6] = v;
  __syncthreads();
  return (red[0] + red[1]) + (red[2] + red[3]);
}

// ---------------------------------------------------------------- embed
__global__ void embed_k(const int* __restrict__ ids, const float* __restrict__ we,
                        const float* __restrict__ pe, float* __restrict__ x) {
  const int row = blockIdx.x, t = threadIdx.x;
  const long id = ids[row];
  float4 a = *(const float4*)(we + id * (long)DEMB + t * 4);
  float4 b = *(const float4*)(pe + (long)row * DEMB + t * 4);
  float4 o; o.x = a.x + b.x; o.y = a.y + b.y; o.z = a.z + b.z; o.w = a.w + b.w;
  *(float4*)(x + (long)row * DEMB + t * 4) = o;
}

// ---------------------------------------------------------------- layernorm
// writes bf16 xn; if xupd != null, also writes xupd_row = x_row + xn_row (fp32)
__global__ void __launch_bounds__(256)
ln_k(const float* __restrict__ x, const float* __restrict__ g,
     const float* __restrict__ b, bf16_t* __restrict__ xn,
     float* __restrict__ xupd) {
  __shared__ float red[4];
  const int row = blockIdx.x, t = threadIdx.x;
  const float* xr = x + (long)row * DEMB;
  float4 v = *(const float4*)(xr + t * 4);
  float mu = blockSum(v.x + v.y + v.z + v.w, red) * (1.0f / DEMB);
  float dx = v.x - mu, dy = v.y - mu, dz = v.z - mu, dw = v.w - mu;
  float var = blockSum(dx * dx + dy * dy + dz * dz + dw * dw, red) * (1.0f / DEMB);
  float inv = 1.0f / sqrtf(var);
  float4 gv = *(const float4*)(g + t * 4);
  float4 bv = *(const float4*)(b + t * 4);
  float o0 = gv.x * dx * inv + bv.x;
  float o1 = gv.y * dy * inv + bv.y;
  float o2 = gv.z * dz * inv + bv.z;
  float o3 = gv.w * dw * inv + bv.w;
  PackU p0, p1;
  p0.h[0] = (bf16_t)o0; p0.h[1] = (bf16_t)o1;
  p1.h[0] = (bf16_t)o2; p1.h[1] = (bf16_t)o3;
  uint2 st; st.x = p0.u; st.y = p1.u;
  *(uint2*)(xn + (long)row * DEMB + t * 4) = st;
  if (xupd) {
    float4 nv; nv.x = v.x + o0; nv.y = v.y + o1; nv.z = v.z + o2; nv.w = v.w + o3;
    *(float4*)(xupd + (long)row * DEMB + t * 4) = nv;
  }
}

// ---------------------------------------------------------------- GEMM
// C[m][n] = sum_k A[m][k] * B[k][n] (+bias). A bf16 row-major lda=K.
// BT=false: B row-major (K x N). BF32 selects fp32 weights (converted) vs bf16.
// BT=true : B is (N x K) row-major bf16 (ldb=K)  [used for Q @ K^T].
// MODE: 0 = store bf16, 1 = fp32 +=, 2 = fp32 store, 3 = gelu -> bf16.
// LDS rows: 17 words (34 bf16, 32 used) -> odd stride, <=4-way bank conflicts.
template<int MODE, bool BT, bool BF32, bool CAUSAL, bool TRIMK>
__global__ void __launch_bounds__(256)
gemm_k(const bf16_t* __restrict__ A, const void* __restrict__ Bv,
       const float* __restrict__ bias, void* __restrict__ Cv,
       int M, int N, int K, long aB, long bB, long cB, int biasB) {
  __shared__ u32 lds[2 * 128 * 17];
  u32* ldsA = lds;
  u32* ldsB = lds + 128 * 17;

  const int t = threadIdx.x;
  const int bz = blockIdx.z;
  const int m0 = blockIdx.y * 128;
  const int n0 = blockIdx.x * 128;
  if (CAUSAL && n0 > m0 + 127) return;

  const bf16_t* Ap = A + (long)bz * aB;
  const int kEnd = TRIMK ? min(K, m0 + 128) : K;

  f32x4 acc[4][4] = {};

  const int lane = t & 63;
  const int wid = t >> 6;
  const int wr = (wid >> 1) * 64;        // wave row offset in tile
  const int wc = (wid & 1) * 64;         // wave col offset in tile
  const int fr = lane & 15;
  const int fg = lane >> 4;

  const int arow0 = t >> 2;              // staging: rows 0..63 (+64 on rnd 1)
  const int akc = (t & 3) * 8;           // k-chunk of 8 bf16
  const int bq = t & 31, bkg = t >> 5;   // B staging: n-quad, k-group

  for (int k0 = 0; k0 < kEnd; k0 += 32) {
    __syncthreads();
    // ---- stage A (128 x 32 bf16)
    #pragma unroll
    for (int rnd = 0; rnd < 2; ++rnd) {
      int row = arow0 + rnd * 64;
      const uint4 d = *(const uint4*)(Ap + (long)(m0 + row) * K + (k0 + akc));
      u32* wp = ldsA + row * 17 + (akc >> 1);
      wp[0] = d.x; wp[1] = d.y; wp[2] = d.z; wp[3] = d.w;
    }
    // ---- stage B into [n][k] K-contiguous layout
    if (BT) {
      const bf16_t* B = (const bf16_t*)Bv + (long)bz * bB;
      #pragma unroll
      for (int rnd = 0; rnd < 2; ++rnd) {
        int row = arow0 + rnd * 64;
        const uint4 d = *(const uint4*)(B + (long)(n0 + row) * K + (k0 + akc));
        u32* wp = ldsB + row * 17 + (akc >> 1);
        wp[0] = d.x; wp[1] = d.y; wp[2] = d.z; wp[3] = d.w;
      }
    } else {
      const int n = n0 + bq * 4;
      bf16_t mb[4][4];
      if (BF32) {
        const float* B = (const float*)Bv + (long)bz * bB;
        #pragma unroll
        for (int j = 0; j < 4; ++j) {
          if (n < N) {
            float4 L = *(const float4*)(B + (long)(k0 + bkg * 4 + j) * N + n);
            mb[j][0] = (bf16_t)L.x; mb[j][1] = (bf16_t)L.y;
            mb[j][2] = (bf16_t)L.z; mb[j][3] = (bf16_t)L.w;
          } else {
            mb[j][0] = mb[j][1] = mb[j][2] = mb[j][3] = (bf16_t)0.0f;
          }
        }
      } else {
        const bf16_t* B = (const bf16_t*)Bv + (long)bz * bB;
        #pragma unroll
        for (int j = 0; j < 4; ++j) {
          if (n < N) {
            const uint2 L = *(const uint2*)(B + (long)(k0 + bkg * 4 + j) * N + n);
            PackU q0, q1; q0.u = L.x; q1.u = L.y;
            mb[j][0] = q0.h[0]; mb[j][1] = q0.h[1];
            mb[j][2] = q1.h[0]; mb[j][3] = q1.h[1];
          } else {
            mb[j][0] = mb[j][1] = mb[j][2] = mb[j][3] = (bf16_t)0.0f;
          }
        }
      }
      #pragma unroll
      for (int i = 0; i < 4; ++i) {   // in-register 4x4 transpose, pack k-pairs
        PackU a0, a1;
        a0.h[0] = mb[0][i]; a0.h[1] = mb[1][i];
        a1.h[0] = mb[2][i]; a1.h[1] = mb[3][i];
        u32* wp = ldsB + (bq * 4 + i) * 17 + bkg * 2;
        wp[0] = a0.u; wp[1] = a1.u;
      }
    }
    __syncthreads();

    // ---- fragments + MFMA
    FragU af[4], bfr[4];
    #pragma unroll
    for (int ms = 0; ms < 4; ++ms) {
      const u32* p = ldsA + (wr + ms * 16 + fr) * 17 + fg * 4;
      af[ms].u[0] = p[0]; af[ms].u[1] = p[1]; af[ms].u[2] = p[2]; af[ms].u[3] = p[3];
    }
    #pragma unroll
    for (int ns = 0; ns < 4; ++ns) {
      const u32* p = ldsB + (wc + ns * 16 + fr) * 17 + fg * 4;
      bfr[ns].u[0] = p[0]; bfr[ns].u[1] = p[1]; bfr[ns].u[2] = p[2]; bfr[ns].u[3] = p[3];
    }
    #pragma unroll
    for (int ms = 0; ms < 4; ++ms)
      #pragma unroll
      for (int ns = 0; ns < 4; ++ns)
        acc[ms][ns] = __builtin_amdgcn_mfma_f32_16x16x32_bf16(
            af[ms].v, bfr[ns].v, acc[ms][ns], 0, 0, 0);
  }

  // ---- epilogue
  #pragma unroll
  for (int ms = 0; ms < 4; ++ms) {
    #pragma unroll
    for (int ns = 0; ns < 4; ++ns) {
      const int col = n0 + wc + ns * 16 + fr;
      if (col >= N) continue;
      const float bvv = bias ? bias[(long)bz * biasB + col] : 0.0f;
      #pragma unroll
      for (int r = 0; r < 4; ++r) {
        const int row = m0 + wr + ms * 16 + fg * 4 + r;
        float v = acc[ms][ns][r] + bvv;
        const long idx = (long)bz * cB + (long)row * N + col;
        if (MODE == 0) {
          ((bf16_t*)Cv)[idx] = (bf16_t)v;
        } else if (MODE == 1) {
          ((float*)Cv)[idx] += v;
        } else if (MODE == 2) {
          ((float*)Cv)[idx] = v;
        } else {
          float gl = 0.5f * v * (1.0f + tanhf(0.7978845608028654f * (v + 0.044715f * v * v * v)));
          ((bf16_t*)Cv)[idx] = (bf16_t)gl;
        }
      }
    }
  }
}

// ---------------------------------------------------------------- causal softmax over scores
__global__ void __launch_bounds__(256)
smax_k(const float* __restrict__ s, bf16_t* __restrict__ a) {
  __shared__ float pbuf[SEQ];
  __shared__ float red[4];
  const int q = blockIdx.x, h = blockIdx.y, t = threadIdx.x;
  const float* sr = s + ((long)h * SEQ + q) * SEQ;
  bf16_t* ar = a + ((long)h * SEQ + q) * SEQ;
  const int L = q + 1;
  const float scale = 0.03125f;  // 1/sqrt(1024)
  float m = -1e30f;
  for (int k = t; k < L; k += 256) m = fmaxf(m, sr[k] * scale);
  #pragma unroll
  for (int o = 32; o > 0; o >>= 1) m = fmaxf(m, __shfl_down(m, o, 64));
  if ((t & 63) == 0) red[t >> 6] = m;
  __syncthreads();
  m = fmaxf(fmaxf(red[0], red[1]), fmaxf(red[2], red[3]));
  float sum = 0.0f;
  for (int k = t; k < L; k += 256) {
    float e = expf(sr[k] * scale - m);
    pbuf[k] = e;
    sum += e;
  }
  #pragma unroll
  for (int o = 32; o > 0; o >>= 1) sum += __shfl_down(sum, o, 64);
  __syncthreads();
  if ((t & 63) == 0) red[t >> 6] = sum;
  __syncthreads();
  sum = (red[0] + red[1]) + (red[2] + red[3]);
  const float inv = 1.0f / sum;
  for (int k = t; k < SEQ; k += 256)
    ar[k] = (k < L) ? (bf16_t)(pbuf[k] * inv) : (bf16_t)0.0f;
}

// ---------------------------------------------------------------- y assembly (overlapping-slice semantics)
__global__ void yasm_k(const bf16_t* __restrict__ o, bf16_t* __restrict__ y) {
  const int row = blockIdx.x, t = threadIdx.x;
  #pragma unroll
  for (int i = 0; i < 4; ++i) {
    const int c = t * 4 + i;
    bf16_t val = (bf16_t)0.0f;
    if (c < NHEAD + DVDIM - 1) {   // 79 live columns
      const int hh = min(NHEAD - 1, c);
      val = o[((long)hh * SEQ + row) * DVDIM + (c - hh)];
    }
    y[(long)row * (NHEAD * DVDIM) + c] = val;
  }
}

// ---------------------------------------------------------------- final vocab softmax (in-place on d_out)
__global__ void __launch_bounds__(256)
vsmax_k(float* __restrict__ out) {
  __shared__ float rm[4], rs[4];
  const int row = blockIdx.x, t = threadIdx.x;
  float* r = out + (long)row * NVOCAB;
  float m = -1e30f, s = 0.0f;
  for (int k = t; k < NVOCAB; k += 256) {
    const float v = r[k];
    if (v > m) { s *= expf(m - v); m = v; }
    s += expf(v - m);
  }
  #pragma unroll
  for (int o = 32; o > 0; o >>= 1) {
    const float mo = __shfl_down(m, o, 64);
    const float so = __shfl_down(s, o, 64);
    const float M2 = fmaxf(m, mo);
    s = s * expf(m - M2) + so * expf(mo - M2);
    m = M2;
  }
  if ((t & 63) == 0) { rm[t >> 6] = m; rs[t >> 6] = s; }
  __syncthreads();
  const float M = fmaxf(fmaxf(rm[0], rm[1]), fmaxf(rm[2], rm[3]));
  const float S = rs[0] * expf(rm[0] - M) + rs[1] * expf(rm[1] - M) +
                  rs[2] * expf(rm[2] - M) + rs[3] * expf(rm[3] - M);
  const float inv = 1.0f / S;
  for (int k = t; k < NVOCAB; k += 256) r[k] = expf(r[k] - M) * inv;
}

// ---------------------------------------------------------------- launch
extern "C" void kernel_launch(void* const* d_in, const int* in_sizes, int n_in,
                              void* d_out, int out_size, void* d_ws, size_t ws_size,
                              hipStream_t stream) {
  (void)in_sizes; (void)n_in; (void)out_size; (void)ws_size;
  const int*   x_ids = (const int*)  d_in[0];
  const float* wemb  = (const float*)d_in[1];
  const float* pemb  = (const float*)d_in[2];
  const float* Wq    = (const float*)d_in[3];
  const float* bq    = (const float*)d_in[4];
  const float* Wk    = (const float*)d_in[5];
  const float* bk    = (const float*)d_in[6];
  const float* Wv    = (const float*)d_in[7];
  const float* bv    = (const float*)d_in[8];
  const float* Wo    = (const float*)d_in[9];
  const float* bo    = (const float*)d_in[10];
  const float* g1    = (const float*)d_in[11];
  const float* b1    = (const float*)d_in[12];
  const float* g2    = (const float*)d_in[13];
  const float* b2    = (const float*)d_in[14];
  const float* W1    = (const float*)d_in[15];
  const float* bm1   = (const float*)d_in[16];
  const float* W2    = (const float*)d_in[17];
  const float* bm2   = (const float*)d_in[18];
  const float* gf    = (const float*)d_in[19];
  const float* bfin  = (const float*)d_in[20];
  const float* Wu    = (const float*)d_in[21];
  const float* bu    = (const float*)d_in[22];

  char* ws = (char*)d_ws;                               // 84 MB used
  float*  X   = (float*) ws;                            //  4 MB fp32 residual
  bf16_t* ACT = (bf16_t*)(ws + (4u  << 20));            //  2 MB xn / xn2 / xf
  bf16_t* Vb  = (bf16_t*)(ws + (6u  << 20));            //  2 MB
  bf16_t* Ob  = (bf16_t*)(ws + (8u  << 20));            //  2 MB
  bf16_t* Yb  = (bf16_t*)(ws + (10u << 20));            //  2 MB
  bf16_t* H1  = (bf16_t*)(ws + (12u << 20));            //  8 MB
  bf16_t* Qb  = (bf16_t*)(ws + (20u << 20));            // 32 MB
  bf16_t* Kb  = (bf16_t*)(ws + (52u << 20));            // 32 MB

  // d_out (131 MB) doubles as scratch for scores (64 MB) + probs (32 MB)
  float*  Sb  = (float*)d_out;
  bf16_t* Ab  = (bf16_t*)((char*)d_out + (64u << 20));
  float*  OUT = (float*)d_out;

  embed_k<<<SEQ, 256, 0, stream>>>(x_ids, wemb, pemb, X);

  for (int l = 0; l < NLAYER; ++l) {
    ln_k<<<SEQ, 256, 0, stream>>>(X, g1 + l * DEMB, b1 + l * DEMB, ACT, nullptr);
    // Q, K, V projections (per-head weight blocks via blockIdx.z)
    gemm_k<0, false, true, false, false><<<dim3(8, 8, 16), 256, 0, stream>>>(
        ACT, Wq + (long)l * NHEAD * DEMB * DEMB, bq + (long)l * NHEAD * DEMB, Qb,
        SEQ, DEMB, DEMB, 0L, (long)DEMB * DEMB, (long)SEQ * DEMB, DEMB);
    gemm_k<0, false, true, false, false><<<dim3(8, 8, 16), 256, 0, stream>>>(
        ACT, Wk + (long)l * NHEAD * DEMB * DEMB, bk + (long)l * NHEAD * DEMB, Kb,
        SEQ, DEMB, DEMB, 0L, (long)DEMB * DEMB, (long)SEQ * DEMB, DEMB);
    gemm_k<0, false, true, false, false><<<dim3(1, 8, 16), 256, 0, stream>>>(
        ACT, Wv + (long)l * NHEAD * DEMB * DVDIM, bv + (long)l * NHEAD * DVDIM, Vb,
        SEQ, DVDIM, DEMB, 0L, (long)DEMB * DVDIM, (long)SEQ * DVDIM, DVDIM);
    // scores S = Q @ K^T (causal blocks only)
    gemm_k<2, true, false, true, false><<<dim3(8, 8, 16), 256, 0, stream>>>(
        Qb, Kb, nullptr, Sb,
        SEQ, SEQ, DEMB, (long)SEQ * DEMB, (long)SEQ * DEMB, (long)SEQ * SEQ, 0);
    smax_k<<<dim3(SEQ, NHEAD), 256, 0, stream>>>(Sb, Ab);
    // O = A @ V (K-loop trimmed to causal extent)
    gemm_k<0, false, false, false, true><<<dim3(1, 8, 16), 256, 0, stream>>>(
        Ab, Vb, nullptr, Ob,
        SEQ, DVDIM, SEQ, (long)SEQ * SEQ, (long)SEQ * DVDIM, (long)SEQ * DVDIM, 0);
    yasm_k<<<SEQ, 256, 0, stream>>>(Ob, Yb);
    // x += y @ Wo + bo
    gemm_k<1, false, true, false, false><<<dim3(8, 8, 1), 256, 0, stream>>>(
        Yb, Wo + (long)l * DEMB * DEMB, bo + (long)l * DEMB, X,
        SEQ, DEMB, DEMB, 0L, 0L, 0L, 0);
    // LN2; also x += xn2 in the same kernel
    ln_k<<<SEQ, 256, 0, stream>>>(X, g2 + l * DEMB, b2 + l * DEMB, ACT, X);
    // MLP
    gemm_k<3, false, true, false, false><<<dim3(32, 8, 1), 256, 0, stream>>>(
        ACT, W1 + (long)l * DEMB * DMLP, bm1 + (long)l * DMLP, H1,
        SEQ, DMLP, DEMB, 0L, 0L, 0L, 0);
    gemm_k<1, false, true, false, false><<<dim3(8, 8, 1), 256, 0, stream>>>(
        H1, W2 + (long)l * DMLP * DEMB, bm2 + (long)l * DEMB, X,
        SEQ, DEMB, DMLP, 0L, 0L, 0L, 0);
  }

  ln_k<<<SEQ, 256, 0, stream>>>(X, gf, bfin, ACT, nullptr);
  gemm_k<2, false, true, false, false><<<dim3(250, 8, 1), 256, 0, stream>>>(
      ACT, Wu, bu, OUT, SEQ, NVOCAB, DEMB, 0L, 0L, 0L, 0);
  vsmax_k<<<SEQ, 256, 0, stream>>>(OUT);
}

// Round 2
// 1970.331 us; speedup vs baseline: 2.3874x; 2.3874x over previous
//
#include <hip/hip_runtime.h>

typedef __bf16 bf16_t;
typedef __bf16 bf16x8 __attribute__((ext_vector_type(8)));
typedef float f32x4 __attribute__((ext_vector_type(4)));
typedef unsigned int u32;

#define SEQ    1024
#define DEMB   1024
#define NHEAD  16
#define DVDIM  64
#define DMLP   4096
#define NVOCAB 32000
#define NLAYER 4

typedef const __attribute__((address_space(1))) void gas_t;
typedef __attribute__((address_space(3))) void las_t;

__device__ __forceinline__ void gload_lds16(const void* g, void* l) {
  __builtin_amdgcn_global_load_lds((gas_t*)g, (las_t*)l, 16, 0, 0);
}

union PackU { bf16_t h[2]; u32 u; };
union B4U  { uint2 u; bf16_t h[4]; };

// ---------------------------------------------------------------- reductions
__device__ __forceinline__ float blockSum(float v, float* red) {
  #pragma unroll
  for (int o = 32; o > 0; o >>= 1) v += __shfl_down(v, o, 64);
  __syncthreads();
  if ((threadIdx.x & 63) == 0) red[threadIdx.x >> 6] = v;
  __syncthreads();
  return (red[0] + red[1]) + (red[2] + red[3]);
}
__device__ __forceinline__ float blockMax(float v, float* red) {
  #pragma unroll
  for (int o = 32; o > 0; o >>= 1) v = fmaxf(v, __shfl_down(v, o, 64));
  __syncthreads();
  if ((threadIdx.x & 63) == 0) red[threadIdx.x >> 6] = v;
  __syncthreads();
  return fmaxf(fmaxf(red[0], red[1]), fmaxf(red[2], red[3]));
}

// ---------------------------------------------------------------- embed
__global__ void embed_k(const int* __restrict__ ids, const float* __restrict__ we,
                        const float* __restrict__ pe, float* __restrict__ x) {
  const int row = blockIdx.x, t = threadIdx.x;
  const long id = ids[row];
  float4 a = *(const float4*)(we + id * (long)DEMB + t * 4);
  float4 b = *(const float4*)(pe + (long)row * DEMB + t * 4);
  float4 o; o.x = a.x + b.x; o.y = a.y + b.y; o.z = a.z + b.z; o.w = a.w + b.w;
  *(float4*)(x + (long)row * DEMB + t * 4) = o;
}

// ---------------------------------------------------------------- layernorm
__global__ void __launch_bounds__(256)
ln_k(const float* __restrict__ x, const float* __restrict__ g,
     const float* __restrict__ b, bf16_t* __restrict__ xn,
     float* __restrict__ xupd) {
  __shared__ float red[4];
  const int row = blockIdx.x, t = threadIdx.x;
  const float* xr = x + (long)row * DEMB;
  float4 v = *(const float4*)(xr + t * 4);
  float mu = blockSum(v.x + v.y + v.z + v.w, red) * (1.0f / DEMB);
  float dx = v.x - mu, dy = v.y - mu, dz = v.z - mu, dw = v.w - mu;
  float var = blockSum(dx * dx + dy * dy + dz * dz + dw * dw, red) * (1.0f / DEMB);
  float inv = 1.0f / sqrtf(var);
  float4 gv = *(const float4*)(g + t * 4);
  float4 bv = *(const float4*)(b + t * 4);
  float o0 = gv.x * dx * inv + bv.x;
  float o1 = gv.y * dy * inv + bv.y;
  float o2 = gv.z * dz * inv + bv.z;
  float o3 = gv.w * dw * inv + bv.w;
  PackU p0, p1;
  p0.h[0] = (bf16_t)o0; p0.h[1] = (bf16_t)o1;
  p1.h[0] = (bf16_t)o2; p1.h[1] = (bf16_t)o3;
  uint2 st; st.x = p0.u; st.y = p1.u;
  *(uint2*)(xn + (long)row * DEMB + t * 4) = st;
  if (xupd) {
    float4 nv; nv.x = v.x + o0; nv.y = v.y + o1; nv.z = v.z + o2; nv.w = v.w + o3;
    *(float4*)(xupd + (long)row * DEMB + t * 4) = nv;
  }
}

// ---------------------------------------------------------------- transpose-convert fp32 (R x C) -> bf16 (C x R)
__global__ void __launch_bounds__(256)
tconv_k(const float* __restrict__ in, bf16_t* __restrict__ out,
        int R, int C, long inB, long outB) {
  __shared__ bf16_t tile[32][33];
  const int z = blockIdx.z;
  const int c0 = blockIdx.x * 32, r0 = blockIdx.y * 32;
  const int tx = threadIdx.x & 31, ty = threadIdx.x >> 5;
  const float* ip = in + (long)z * inB;
  bf16_t* op = out + (long)z * outB;
  #pragma unroll
  for (int i = 0; i < 4; ++i)
    tile[ty + i * 8][tx] = (bf16_t)ip[(long)(r0 + ty + i * 8) * C + (c0 + tx)];
  __syncthreads();
  #pragma unroll
  for (int i = 0; i < 4; ++i)
    op[(long)(c0 + ty + i * 8) * R + (r0 + tx)] = tile[tx][ty + i * 8];
}

// ---------------------------------------------------------------- GEMM (m97 structure)
// C[m][n] = sum_k A[m][k]*B[n][k] (+bias).  A: M x K bf16 k-contig.
// B: N x K bf16 k-contig (i.e. B^T of the math's K x N matrix).
// global_load_lds 16B staging into linear LDS [rows][32] bf16.
// MODE: 0 bf16 store, 1 fp32 +=, 2 fp32 store, 3 gelu->bf16, 4 bf16 store transposed [n][m].
template<int MODE, int BN, bool CAUSAL, bool TRIMK>
__global__ void __launch_bounds__(256)
gemm_k(const bf16_t* __restrict__ A, const bf16_t* __restrict__ B,
       const float* __restrict__ bias, void* __restrict__ Cv,
       int M, int N, int K, long aB, long bB, long cB, int biasB) {
  __shared__ bf16_t lsA[128 * 32];
  __shared__ bf16_t lsB[BN * 32];

  const int t = threadIdx.x;
  const int bz = blockIdx.z;
  const int m0 = blockIdx.y * 128;
  const int n0 = blockIdx.x * BN;
  if (CAUSAL && n0 > m0 + 127) return;

  const bf16_t* Ap = A + (long)bz * aB;
  const bf16_t* Bp = B + (long)bz * bB;
  const int kEnd = TRIMK ? min(K, m0 + 128) : K;

  constexpr int NS = BN / 32;            // n-frags per wave
  const int lane = t & 63;
  const int wid = t >> 6;
  const int wr = (wid >> 1) * 64;
  const int wc = (wid & 1) * (BN / 2);
  const int fr = lane & 15, fg = lane >> 4;
  const int srow = lane >> 2;            // staging row within 16-row segment
  const int skc  = (lane & 3) * 8;       // staging k-chunk (8 bf16 = 16B)

  f32x4 acc[4][NS] = {};

  for (int k0 = 0; k0 < kEnd; k0 += 32) {
    if (k0) __syncthreads();
    #pragma unroll
    for (int i = 0; i < 2; ++i) {        // A: 8 segs x 1KB, 2 per wave
      const int seg = wid * 2 + i;
      gload_lds16(Ap + (long)(m0 + seg * 16 + srow) * K + (k0 + skc),
                  lsA + seg * 512);
    }
    if (BN == 128) {
      #pragma unroll
      for (int i = 0; i < 2; ++i) {
        const int seg = wid * 2 + i;
        gload_lds16(Bp + (long)(n0 + seg * 16 + srow) * K + (k0 + skc),
                    lsB + seg * 512);
      }
    } else {                             // BN=64: 4 segs, 1 per wave
      gload_lds16(Bp + (long)(n0 + wid * 16 + srow) * K + (k0 + skc),
                  lsB + wid * 512);
    }
    __syncthreads();

    bf16x8 af[4], bfv[NS];
    #pragma unroll
    for (int ms = 0; ms < 4; ++ms)
      af[ms] = *(const bf16x8*)(lsA + (wr + ms * 16 + fr) * 32 + fg * 8);
    #pragma unroll
    for (int ns = 0; ns < NS; ++ns)
      bfv[ns] = *(const bf16x8*)(lsB + (wc + ns * 16 + fr) * 32 + fg * 8);
    #pragma unroll
    for (int ms = 0; ms < 4; ++ms)
      #pragma unroll
      for (int ns = 0; ns < NS; ++ns)
        acc[ms][ns] = __builtin_amdgcn_mfma_f32_16x16x32_bf16(
            af[ms], bfv[ns], acc[ms][ns], 0, 0, 0);
  }

  #pragma unroll
  for (int ms = 0; ms < 4; ++ms) {
    #pragma unroll
    for (int ns = 0; ns < NS; ++ns) {
      const int col = n0 + wc + ns * 16 + fr;
      const float bvv = bias ? bias[(long)bz * biasB + col] : 0.0f;
      #pragma unroll
      for (int r = 0; r < 4; ++r) {
        const int row = m0 + wr + ms * 16 + fg * 4 + r;
        float v = acc[ms][ns][r] + bvv;
        if (MODE == 0) {
          ((bf16_t*)Cv)[(long)bz * cB + (long)row * N + col] = (bf16_t)v;
        } else if (MODE == 1) {
          ((float*)Cv)[(long)row * N + col] += v;
        } else if (MODE == 2) {
          ((float*)Cv)[(long)row * N + col] = v;
        } else if (MODE == 3) {
          float gl = 0.5f * v * (1.0f + tanhf(0.7978845608028654f * (v + 0.044715f * v * v * v)));
          ((bf16_t*)Cv)[(long)row * N + col] = (bf16_t)gl;
        } else {
          ((bf16_t*)Cv)[(long)col * M + row] = (bf16_t)v;   // transposed store
        }
      }
    }
  }
}

// ---------------------------------------------------------------- causal softmax, in-place on bf16 scores
__global__ void __launch_bounds__(256)
smax_k(bf16_t* __restrict__ s) {
  __shared__ float red[4];
  const int q = blockIdx.x, h = blockIdx.y, t = threadIdx.x;
  bf16_t* sr = s + ((long)h * SEQ + q) * SEQ;
  const int L = q + 1;
  const float scale = 0.03125f;          // 1/sqrt(1024)
  B4U b; b.u = *(const uint2*)(sr + t * 4);
  float x[4];
  float m = -1e30f;
  #pragma unroll
  for (int j = 0; j < 4; ++j) {
    x[j] = (float)b.h[j] * scale;
    if (t * 4 + j < L) m = fmaxf(m, x[j]);
  }
  m = blockMax(m, red);
  float e[4], sum = 0.0f;
  #pragma unroll
  for (int j = 0; j < 4; ++j) {
    e[j] = (t * 4 + j < L) ? expf(x[j] - m) : 0.0f;
    sum += e[j];
  }
  __syncthreads();
  sum = blockSum(sum, red);
  const float inv = 1.0f / sum;
  #pragma unroll
  for (int j = 0; j < 4; ++j) b.h[j] = (bf16_t)(e[j] * inv);
  *(uint2*)(sr + t * 4) = b.u;
}

// ---------------------------------------------------------------- y assembly (1024 x 128 packed)
__global__ void yasm_k(const bf16_t* __restrict__ o, bf16_t* __restrict__ y) {
  const int row = blockIdx.x, t = threadIdx.x;   // 128 threads
  bf16_t val = (bf16_t)0.0f;
  if (t < NHEAD + DVDIM - 1) {                   // 79 live columns
    const int hh = min(NHEAD - 1, t);
    val = o[((long)hh * SEQ + row) * DVDIM + (t - hh)];
  }
  y[(long)row * 128 + t] = val;
}

// ---------------------------------------------------------------- final vocab softmax (in-place fp32)
__global__ void __launch_bounds__(256)
vsmax_k(float* __restrict__ out) {
  __shared__ float rm[4], rs[4];
  const int row = blockIdx.x, t = threadIdx.x;
  float* r = out + (long)row * NVOCAB;
  float m = -1e30f, s = 0.0f;
  for (int k = t; k < NVOCAB; k += 256) {
    const float v = r[k];
    if (v > m) { s *= expf(m - v); m = v; }
    s += expf(v - m);
  }
  #pragma unroll
  for (int o = 32; o > 0; o >>= 1) {
    const float mo = __shfl_down(m, o, 64);
    const float so = __shfl_down(s, o, 64);
    const float M2 = fmaxf(m, mo);
    s = s * expf(m - M2) + so * expf(mo - M2);
    m = M2;
  }
  if ((t & 63) == 0) { rm[t >> 6] = m; rs[t >> 6] = s; }
  __syncthreads();
  const float M = fmaxf(fmaxf(rm[0], rm[1]), fmaxf(rm[2], rm[3]));
  const float S = rs[0] * expf(rm[0] - M) + rs[1] * expf(rm[1] - M) +
                  rs[2] * expf(rm[2] - M) + rs[3] * expf(rm[3] - M);
  const float inv = 1.0f / S;
  for (int k = t; k < NVOCAB; k += 256) r[k] = expf(r[k] - M) * inv;
}

// ---------------------------------------------------------------- launch
extern "C" void kernel_launch(void* const* d_in, const int* in_sizes, int n_in,
                              void* d_out, int out_size, void* d_ws, size_t ws_size,
                              hipStream_t stream) {
  (void)in_sizes; (void)n_in; (void)out_size; (void)ws_size;
  const int*   x_ids = (const int*)  d_in[0];
  const float* wemb  = (const float*)d_in[1];
  const float* pemb  = (const float*)d_in[2];
  const float* Wq    = (const float*)d_in[3];
  const float* bq    = (const float*)d_in[4];
  const float* Wk    = (const float*)d_in[5];
  const float* bk    = (const float*)d_in[6];
  const float* Wv    = (const float*)d_in[7];
  const float* bv    = (const float*)d_in[8];
  const float* Wo    = (const float*)d_in[9];
  const float* bo    = (const float*)d_in[10];
  const float* g1    = (const float*)d_in[11];
  const float* b1    = (const float*)d_in[12];
  const float* g2    = (const float*)d_in[13];
  const float* b2    = (const float*)d_in[14];
  const float* W1    = (const float*)d_in[15];
  const float* bm1   = (const float*)d_in[16];
  const float* W2    = (const float*)d_in[17];
  const float* bm2   = (const float*)d_in[18];
  const float* gf    = (const float*)d_in[19];
  const float* bfin  = (const float*)d_in[20];
  const float* Wu    = (const float*)d_in[21];
  const float* bu    = (const float*)d_in[22];

  char* ws = (char*)d_ws;                               // 84 MiB footprint (same as r0)
  float*  X   = (float*) ws;                            //  4 MiB fp32 residual
  bf16_t* ACT = (bf16_t*)(ws + (4u  << 20));            //  2 MiB
  bf16_t* VbT = (bf16_t*)(ws + (6u  << 20));            //  2 MiB  [h*64+v][seq]
  bf16_t* Ob  = (bf16_t*)(ws + (8u  << 20));            //  2 MiB  [h][q][v]
  bf16_t* Yb  = (bf16_t*)(ws + (10u << 20));            //  0.25 MiB [q][128]
  bf16_t* H1  = (bf16_t*)(ws + (12u << 20));            //  8 MiB
  bf16_t* Qb  = (bf16_t*)(ws + (20u << 20));            // 32 MiB [h][q][e]
  bf16_t* Kb  = (bf16_t*)(ws + (52u << 20));            // 32 MiB [h][kv][e]
  bf16_t* WuT = (bf16_t*)(ws + (20u << 20));            // 62.5 MiB (Qb/Kb dead by then)

  bf16_t* Sb  = (bf16_t*)d_out;                         // 32 MiB scores->probs (bf16, in-place)
  bf16_t* WT  = (bf16_t*)((char*)d_out + (32u << 20));  // <=32 MiB bf16 transposed weights
  float*  OUT = (float*)d_out;

  const long DD = (long)DEMB * DEMB;

  embed_k<<<SEQ, 256, 0, stream>>>(x_ids, wemb, pemb, X);

  for (int l = 0; l < NLAYER; ++l) {
    ln_k<<<SEQ, 256, 0, stream>>>(X, g1 + l * DEMB, b1 + l * DEMB, ACT, nullptr);

    // Q = xn @ Wq[h] + bq   (B^T staged per head)
    tconv_k<<<dim3(32, 32, NHEAD), 256, 0, stream>>>(
        Wq + (long)l * NHEAD * DD, WT, DEMB, DEMB, DD, DD);
    gemm_k<0, 128, false, false><<<dim3(8, 8, NHEAD), 256, 0, stream>>>(
        ACT, WT, bq + (long)l * NHEAD * DEMB, Qb,
        SEQ, DEMB, DEMB, 0L, DD, (long)SEQ * DEMB, DEMB);
    // K
    tconv_k<<<dim3(32, 32, NHEAD), 256, 0, stream>>>(
        Wk + (long)l * NHEAD * DD, WT, DEMB, DEMB, DD, DD);
    gemm_k<0, 128, false, false><<<dim3(8, 8, NHEAD), 256, 0, stream>>>(
        ACT, WT, bk + (long)l * NHEAD * DEMB, Kb,
        SEQ, DEMB, DEMB, 0L, DD, (long)SEQ * DEMB, DEMB);
    // V (all heads fused: N = H*DV = 1024), transposed store -> VbT[h*64+v][seq]
    tconv_k<<<dim3(2, 32, NHEAD), 256, 0, stream>>>(
        Wv + (long)l * NHEAD * DEMB * DVDIM, WT, DEMB, DVDIM,
        (long)DEMB * DVDIM, (long)DVDIM * DEMB);
    gemm_k<4, 128, false, false><<<dim3(8, 8, 1), 256, 0, stream>>>(
        ACT, WT, bv + (long)l * NHEAD * DVDIM, VbT,
        SEQ, NHEAD * DVDIM, DEMB, 0L, 0L, 0L, 0);

    // scores S = Q @ K^T (bf16, causal blocks only)
    gemm_k<0, 128, true, false><<<dim3(8, 8, NHEAD), 256, 0, stream>>>(
        Qb, Kb, nullptr, Sb,
        SEQ, SEQ, DEMB, (long)SEQ * DEMB, (long)SEQ * DEMB, (long)SEQ * SEQ, 0);
    smax_k<<<dim3(SEQ, NHEAD), 256, 0, stream>>>(Sb);
    // O = P @ V  (BN=64, K trimmed to causal extent)
    gemm_k<0, 64, false, true><<<dim3(1, 8, NHEAD), 256, 0, stream>>>(
        Sb, VbT, nullptr, Ob,
        SEQ, DVDIM, SEQ, (long)SEQ * SEQ, (long)DVDIM * SEQ, (long)SEQ * DVDIM, 0);
    yasm_k<<<SEQ, 128, 0, stream>>>(Ob, Yb);

    // x += y @ Wo + bo   (only first 128 rows of Wo matter; K=128)
    tconv_k<<<dim3(32, 4, 1), 256, 0, stream>>>(
        Wo + (long)l * DD, WT, 128, DEMB, 0L, 0L);
    gemm_k<1, 128, false, false><<<dim3(8, 8, 1), 256, 0, stream>>>(
        Yb, WT, bo + (long)l * DEMB, X,
        SEQ, DEMB, 128, 0L, 0L, 0L, 0);

    ln_k<<<SEQ, 256, 0, stream>>>(X, g2 + l * DEMB, b2 + l * DEMB, ACT, X);

    // MLP
    tconv_k<<<dim3(128, 32, 1), 256, 0, stream>>>(
        W1 + (long)l * DEMB * DMLP, WT, DEMB, DMLP, 0L, 0L);
    gemm_k<3, 128, false, false><<<dim3(32, 8, 1), 256, 0, stream>>>(
        ACT, WT, bm1 + (long)l * DMLP, H1,
        SEQ, DMLP, DEMB, 0L, 0L, 0L, 0);
    tconv_k<<<dim3(32, 128, 1), 256, 0, stream>>>(
        W2 + (long)l * DMLP * DEMB, WT, DMLP, DEMB, 0L, 0L);
    gemm_k<1, 128, false, false><<<dim3(8, 8, 1), 256, 0, stream>>>(
        H1, WT, bm2 + (long)l * DEMB, X,
        SEQ, DEMB, DMLP, 0L, 0L, 0L, 0);
  }

  ln_k<<<SEQ, 256, 0, stream>>>(X, gf, bfin, ACT, nullptr);
  tconv_k<<<dim3(1000, 32, 1), 256, 0, stream>>>(Wu, WuT, DEMB, NVOCAB, 0L, 0L);
  gemm_k<2, 128, false, false><<<dim3(250, 8, 1), 256, 0, stream>>>(
      ACT, WuT, bu, OUT, SEQ, NVOCAB, DEMB, 0L, 0L, 0L, 0);
  vsmax_k<<<SEQ, 256, 0, stream>>>(OUT);
}

// Round 3
// 1740.632 us; speedup vs baseline: 2.7024x; 1.1320x over previous
//
#include <hip/hip_runtime.h>

typedef __bf16 bf16_t;
typedef __bf16 bf16x8 __attribute__((ext_vector_type(8)));
typedef float f32x4 __attribute__((ext_vector_type(4)));
typedef unsigned int u32;

#define SEQ    1024
#define DEMB   1024
#define NHEAD  16
#define DVDIM  64
#define DMLP   4096
#define NVOCAB 32000
#define NLAYER 4

typedef const __attribute__((address_space(1))) void gas_t;
typedef __attribute__((address_space(3))) void las_t;

__device__ __forceinline__ void gload_lds16(const void* g, void* l) {
  __builtin_amdgcn_global_load_lds((gas_t*)g, (las_t*)l, 16, 0, 0);
}

union PackU { bf16_t h[2]; u32 u; };
union B4U  { uint2 u; bf16_t h[4]; };

// ---------------------------------------------------------------- reductions
__device__ __forceinline__ float blockSum(float v, float* red) {
  #pragma unroll
  for (int o = 32; o > 0; o >>= 1) v += __shfl_down(v, o, 64);
  __syncthreads();
  if ((threadIdx.x & 63) == 0) red[threadIdx.x >> 6] = v;
  __syncthreads();
  return (red[0] + red[1]) + (red[2] + red[3]);
}
__device__ __forceinline__ float blockMax(float v, float* red) {
  #pragma unroll
  for (int o = 32; o > 0; o >>= 1) v = fmaxf(v, __shfl_down(v, o, 64));
  __syncthreads();
  if ((threadIdx.x & 63) == 0) red[threadIdx.x >> 6] = v;
  __syncthreads();
  return fmaxf(fmaxf(red[0], red[1]), fmaxf(red[2], red[3]));
}

// ---------------------------------------------------------------- embed
__global__ void embed_k(const int* __restrict__ ids, const float* __restrict__ we,
                        const float* __restrict__ pe, float* __restrict__ x) {
  const int row = blockIdx.x, t = threadIdx.x;
  const long id = ids[row];
  float4 a = *(const float4*)(we + id * (long)DEMB + t * 4);
  float4 b = *(const float4*)(pe + (long)row * DEMB + t * 4);
  float4 o; o.x = a.x + b.x; o.y = a.y + b.y; o.z = a.z + b.z; o.w = a.w + b.w;
  *(float4*)(x + (long)row * DEMB + t * 4) = o;
}

// ---------------------------------------------------------------- layernorm
__global__ void __launch_bounds__(256)
ln_k(const float* __restrict__ x, const float* __restrict__ g,
     const float* __restrict__ b, bf16_t* __restrict__ xn,
     float* __restrict__ xupd) {
  __shared__ float red[4];
  const int row = blockIdx.x, t = threadIdx.x;
  const float* xr = x + (long)row * DEMB;
  float4 v = *(const float4*)(xr + t * 4);
  float mu = blockSum(v.x + v.y + v.z + v.w, red) * (1.0f / DEMB);
  float dx = v.x - mu, dy = v.y - mu, dz = v.z - mu, dw = v.w - mu;
  float var = blockSum(dx * dx + dy * dy + dz * dz + dw * dw, red) * (1.0f / DEMB);
  float inv = 1.0f / sqrtf(var);
  float4 gv = *(const float4*)(g + t * 4);
  float4 bv = *(const float4*)(b + t * 4);
  float o0 = gv.x * dx * inv + bv.x;
  float o1 = gv.y * dy * inv + bv.y;
  float o2 = gv.z * dz * inv + bv.z;
  float o3 = gv.w * dw * inv + bv.w;
  PackU p0, p1;
  p0.h[0] = (bf16_t)o0; p0.h[1] = (bf16_t)o1;
  p1.h[0] = (bf16_t)o2; p1.h[1] = (bf16_t)o3;
  uint2 st; st.x = p0.u; st.y = p1.u;
  *(uint2*)(xn + (long)row * DEMB + t * 4) = st;
  if (xupd) {
    float4 nv; nv.x = v.x + o0; nv.y = v.y + o1; nv.z = v.z + o2; nv.w = v.w + o3;
    *(float4*)(xupd + (long)row * DEMB + t * 4) = nv;
  }
}

// ---------------------------------------------------------------- bias concat (bq|bk) -> BIAS[32][DEMB]
__global__ void biascat_k(const float* __restrict__ bq, const float* __restrict__ bk,
                          float* __restrict__ out) {
  const int z = blockIdx.x, t = threadIdx.x;       // 32 blocks x 256 thr x 4 floats
  const float* src = (z < NHEAD) ? (bq + (long)z * DEMB) : (bk + (long)(z - NHEAD) * DEMB);
  *(float4*)(out + (long)z * DEMB + t * 4) = *(const float4*)(src + t * 4);
}

// ---------------------------------------------------------------- transpose-convert fp32 (R x C) -> bf16 (C x R)
// optional second source: z >= zsplit reads from in2 (z-zsplit)
__global__ void __launch_bounds__(256)
tconv_k(const float* __restrict__ in, const float* __restrict__ in2, int zsplit,
        bf16_t* __restrict__ out, int R, int C, long inB, long outB) {
  __shared__ bf16_t tile[32][33];
  const int z = blockIdx.z;
  const int c0 = blockIdx.x * 32, r0 = blockIdx.y * 32;
  const int tx = threadIdx.x & 31, ty = threadIdx.x >> 5;
  const float* ip = (in2 && z >= zsplit) ? (in2 + (long)(z - zsplit) * inB)
                                         : (in + (long)z * inB);
  bf16_t* op = out + (long)z * outB;
  #pragma unroll
  for (int i = 0; i < 4; ++i)
    tile[ty + i * 8][tx] = (bf16_t)ip[(long)(r0 + ty + i * 8) * C + (c0 + tx)];
  __syncthreads();
  #pragma unroll
  for (int i = 0; i < 4; ++i)
    op[(long)(c0 + ty + i * 8) * R + (r0 + tx)] = tile[tx][ty + i * 8];
}

// ---------------------------------------------------------------- 128x128 GEMM (m97 structure) for small/odd shapes
// C[m][n] = sum_k A[m][k]*B[n][k] (+bias). MODE: 0 bf16, 1 fp32 +=, 2 fp32, 3 gelu->bf16, 4 bf16 transposed.
template<int MODE, int BN, bool CAUSAL, bool TRIMK>
__global__ void __launch_bounds__(256)
gemm_k(const bf16_t* __restrict__ A, const bf16_t* __restrict__ B,
       const float* __restrict__ bias, void* __restrict__ Cv,
       int M, int N, int K, long aB, long bB, long cB, int biasB) {
  __shared__ bf16_t lsA[128 * 32];
  __shared__ bf16_t lsB[BN * 32];

  const int t = threadIdx.x;
  const int bz = blockIdx.z;
  const int m0 = blockIdx.y * 128;
  const int n0 = blockIdx.x * BN;
  if (CAUSAL && n0 > m0 + 127) return;

  const bf16_t* Ap = A + (long)bz * aB;
  const bf16_t* Bp = B + (long)bz * bB;
  const int kEnd = TRIMK ? min(K, m0 + 128) : K;

  constexpr int NS = BN / 32;
  const int lane = t & 63;
  const int wid = t >> 6;
  const int wr = (wid >> 1) * 64;
  const int wc = (wid & 1) * (BN / 2);
  const int fr = lane & 15, fg = lane >> 4;
  const int srow = lane >> 2;
  const int skc  = (lane & 3) * 8;

  f32x4 acc[4][NS] = {};

  for (int k0 = 0; k0 < kEnd; k0 += 32) {
    if (k0) __syncthreads();
    #pragma unroll
    for (int i = 0; i < 2; ++i) {
      const int seg = wid * 2 + i;
      gload_lds16(Ap + (long)(m0 + seg * 16 + srow) * K + (k0 + skc),
                  lsA + seg * 512);
    }
    if (BN == 128) {
      #pragma unroll
      for (int i = 0; i < 2; ++i) {
        const int seg = wid * 2 + i;
        gload_lds16(Bp + (long)(n0 + seg * 16 + srow) * K + (k0 + skc),
                    lsB + seg * 512);
      }
    } else {
      gload_lds16(Bp + (long)(n0 + wid * 16 + srow) * K + (k0 + skc),
                  lsB + wid * 512);
    }
    __syncthreads();

    bf16x8 af[4], bfv[NS];
    #pragma unroll
    for (int ms = 0; ms < 4; ++ms)
      af[ms] = *(const bf16x8*)(lsA + (wr + ms * 16 + fr) * 32 + fg * 8);
    #pragma unroll
    for (int ns = 0; ns < NS; ++ns)
      bfv[ns] = *(const bf16x8*)(lsB + (wc + ns * 16 + fr) * 32 + fg * 8);
    #pragma unroll
    for (int ms = 0; ms < 4; ++ms)
      #pragma unroll
      for (int ns = 0; ns < NS; ++ns)
        acc[ms][ns] = __builtin_amdgcn_mfma_f32_16x16x32_bf16(
            af[ms], bfv[ns], acc[ms][ns], 0, 0, 0);
  }

  #pragma unroll
  for (int ms = 0; ms < 4; ++ms) {
    #pragma unroll
    for (int ns = 0; ns < NS; ++ns) {
      const int col = n0 + wc + ns * 16 + fr;
      const float bvv = bias ? bias[(long)bz * biasB + col] : 0.0f;
      #pragma unroll
      for (int r = 0; r < 4; ++r) {
        const int row = m0 + wr + ms * 16 + fg * 4 + r;
        float v = acc[ms][ns][r] + bvv;
        if (MODE == 0) {
          ((bf16_t*)Cv)[(long)bz * cB + (long)row * N + col] = (bf16_t)v;
        } else if (MODE == 1) {
          ((float*)Cv)[(long)row * N + col] += v;
        } else if (MODE == 2) {
          ((float*)Cv)[(long)row * N + col] = v;
        } else if (MODE == 3) {
          float gl = 0.5f * v * (1.0f + tanhf(0.7978845608028654f * (v + 0.044715f * v * v * v)));
          ((bf16_t*)Cv)[(long)row * N + col] = (bf16_t)gl;
        } else {
          ((bf16_t*)Cv)[(long)col * M + row] = (bf16_t)v;
        }
      }
    }
  }
}

// ---------------------------------------------------------------- 256x256 8-phase GEMM (m201 template, plain HIP)
// C[m][n] = sum_k A[m][k]*B[n][k] (+bias). Requires: M%256==0, N%256==0, K%128==0 (NT even).
// 8 waves (2M x 4N), BK=64, 128 KiB LDS double-buffered, swizzled slots (slot ^= row&7),
// counted vmcnt(4) at phases 4/8 only. MODE: 0 bf16 store, 2 fp32 store.
#define GPHASE(buf, mh, nh, STAGE, VM) do {                                            \
  bf16x8 af[4][2], bfv[2][2];                                                          \
  _Pragma("unroll") for (int mf = 0; mf < 4; ++mf) {                                   \
    const int r = wm * 128 + ((mh) * 4 + mf) * 16 + (lane & 15);                       \
    _Pragma("unroll") for (int ks = 0; ks < 2; ++ks) {                                 \
      const int slot = ks * 4 + (lane >> 4);                                           \
      af[mf][ks] = *(const bf16x8*)(lds + (buf) * 32768 + r * 64 +                     \
                                    ((slot ^ (r & 7)) << 3)); } }                      \
  _Pragma("unroll") for (int nf = 0; nf < 2; ++nf) {                                   \
    const int r = wn * 64 + ((nh) * 2 + nf) * 16 + (lane & 15);                        \
    _Pragma("unroll") for (int ks = 0; ks < 2; ++ks) {                                 \
      const int slot = ks * 4 + (lane >> 4);                                           \
      bfv[nf][ks] = *(const bf16x8*)(lds + (buf) * 32768 + 16384 + r * 64 +            \
                                     ((slot ^ (r & 7)) << 3)); } }                     \
  STAGE;                                                                               \
  __builtin_amdgcn_s_barrier();                                                        \
  asm volatile("s_waitcnt lgkmcnt(0)" ::: "memory");                                   \
  __builtin_amdgcn_sched_barrier(0);                                                   \
  __builtin_amdgcn_s_setprio(1);                                                       \
  _Pragma("unroll") for (int mf = 0; mf < 4; ++mf)                                     \
    _Pragma("unroll") for (int nf = 0; nf < 2; ++nf)                                   \
      _Pragma("unroll") for (int ks = 0; ks < 2; ++ks)                                 \
        acc[(mh) * 4 + mf][(nh) * 2 + nf] = __builtin_amdgcn_mfma_f32_16x16x32_bf16(   \
            af[mf][ks], bfv[nf][ks], acc[(mh) * 4 + mf][(nh) * 2 + nf], 0, 0, 0);      \
  __builtin_amdgcn_s_setprio(0);                                                       \
  VM;                                                                                  \
  __builtin_amdgcn_s_barrier();                                                        \
} while (0)

template<int MODE, bool CAUSAL>
__global__ void __launch_bounds__(512, 1)
gemm256_k(const bf16_t* __restrict__ A, const bf16_t* __restrict__ B,
          const float* __restrict__ bias, void* __restrict__ Cv,
          int M, int N, int K, long aB, long bB, long cB, int biasB) {
  __shared__ bf16_t lds[65536];          // 128 KiB: [buf:2][A 16384 | B 16384]

  const int t = threadIdx.x;
  const int lane = t & 63, w = t >> 6;
  const int wm = w >> 2, wn = w & 3;
  const int bz = blockIdx.z;
  const int m0 = blockIdx.y * 256, n0 = blockIdx.x * 256;
  if (CAUSAL && n0 > m0 + 255) return;

  const bf16_t* Ap = A + (long)bz * aB;
  const bf16_t* Bp = B + (long)bz * bB;
  const int NT = K >> 6;                 // K-tiles of 64 (must be even)

  f32x4 acc[8][4] = {};

  // stage one A-half (alpha: row bit6==0 quarters; beta: bit6==1), 2 x gload/thread
  auto stA = [&](int half, int kt, int buf) {
    #pragma unroll
    for (int rr = 0; rr < 2; ++rr) {
      const int rw0 = rr * 64 + w * 8;
      const int row0 = ((rw0 >> 6) << 7) | (half << 6) | (rw0 & 63);
      const int r = row0 + (lane >> 3);
      const int slot = lane & 7;
      gload_lds16(Ap + (long)(m0 + r) * K + (kt << 6) + ((slot ^ (r & 7)) << 3),
                  lds + buf * 32768 + row0 * 64);
    }
  };
  auto stB = [&](int half, int kt, int buf) {   // gamma: row bit5==0; delta: bit5==1
    #pragma unroll
    for (int rr = 0; rr < 2; ++rr) {
      const int rw0 = rr * 64 + w * 8;
      const int row0 = ((rw0 >> 5) << 6) | (half << 5) | (rw0 & 31);
      const int r = row0 + (lane >> 3);
      const int slot = lane & 7;
      gload_lds16(Bp + (long)(n0 + r) * K + (kt << 6) + ((slot ^ (r & 7)) << 3),
                  lds + buf * 32768 + 16384 + row0 * 64);
    }
  };

  // prologue: tile0 fully + tile1 {Bgamma, Aalpha}; drain tile0
  stB(0, 0, 0); stA(0, 0, 0); stA(1, 0, 0); stB(1, 0, 0);
  stB(0, 1, 1); stA(0, 1, 1);
  asm volatile("s_waitcnt vmcnt(4)" ::: "memory");
  __builtin_amdgcn_s_barrier();

  for (int it = 0; it < (NT >> 1); ++it) {
    const int tt = it * 2;
    const int s1 = min(tt + 1, NT - 1);
    const int s2 = min(tt + 2, NT - 1);
    const int s3 = min(tt + 3, NT - 1);
    GPHASE(0, 0, 0, { stA(1, s1, 1); }, );
    GPHASE(0, 1, 0, { stB(1, s1, 1); }, );
    GPHASE(0, 0, 1, { stB(0, s2, 0); }, );
    GPHASE(0, 1, 1, { stA(0, s2, 0); }, asm volatile("s_waitcnt vmcnt(4)" ::: "memory"));
    GPHASE(1, 0, 0, { stA(1, s2, 0); }, );
    GPHASE(1, 1, 0, { stB(1, s2, 0); }, );
    GPHASE(1, 0, 1, { stB(0, s3, 1); }, );
    GPHASE(1, 1, 1, { stA(0, s3, 1); }, asm volatile("s_waitcnt vmcnt(4)" ::: "memory"));
  }
  asm volatile("s_waitcnt vmcnt(0)" ::: "memory");

  #pragma unroll
  for (int mf = 0; mf < 8; ++mf) {
    #pragma unroll
    for (int nf = 0; nf < 4; ++nf) {
      const int col = n0 + wn * 64 + nf * 16 + (lane & 15);
      const float bvv = bias ? bias[(long)bz * biasB + col] : 0.0f;
      #pragma unroll
      for (int r = 0; r < 4; ++r) {
        const int row = m0 + wm * 128 + mf * 16 + (lane >> 4) * 4 + r;
        const float v = acc[mf][nf][r] + bvv;
        if (MODE == 0)
          ((bf16_t*)Cv)[(long)bz * cB + (long)row * N + col] = (bf16_t)v;
        else
          ((float*)Cv)[(long)bz * cB + (long)row * N + col] = v;
      }
    }
  }
}

// ---------------------------------------------------------------- causal softmax, in-place on bf16 scores
__global__ void __launch_bounds__(256)
smax_k(bf16_t* __restrict__ s) {
  __shared__ float red[4];
  const int q = blockIdx.x, h = blockIdx.y, t = threadIdx.x;
  bf16_t* sr = s + ((long)h * SEQ + q) * SEQ;
  const int L = q + 1;
  const float scale = 0.03125f;          // 1/sqrt(1024)
  B4U b; b.u = *(const uint2*)(sr + t * 4);
  float x[4];
  float m = -1e30f;
  #pragma unroll
  for (int j = 0; j < 4; ++j) {
    x[j] = (float)b.h[j] * scale;
    if (t * 4 + j < L) m = fmaxf(m, x[j]);
  }
  m = blockMax(m, red);
  float e[4], sum = 0.0f;
  #pragma unroll
  for (int j = 0; j < 4; ++j) {
    e[j] = (t * 4 + j < L) ? expf(x[j] - m) : 0.0f;
    sum += e[j];
  }
  __syncthreads();
  sum = blockSum(sum, red);
  const float inv = 1.0f / sum;
  #pragma unroll
  for (int j = 0; j < 4; ++j) b.h[j] = (bf16_t)(e[j] * inv);
  *(uint2*)(sr + t * 4) = b.u;
}

// ---------------------------------------------------------------- y assembly (1024 x 128 packed)
__global__ void yasm_k(const bf16_t* __restrict__ o, bf16_t* __restrict__ y) {
  const int row = blockIdx.x, t = threadIdx.x;   // 128 threads
  bf16_t val = (bf16_t)0.0f;
  if (t < NHEAD + DVDIM - 1) {
    const int hh = min(NHEAD - 1, t);
    val = o[((long)hh * SEQ + row) * DVDIM + (t - hh)];
  }
  y[(long)row * 128 + t] = val;
}

// ---------------------------------------------------------------- final vocab softmax (in-place fp32)
__global__ void __launch_bounds__(256)
vsmax_k(float* __restrict__ out) {
  __shared__ float rm[4], rs[4];
  const int row = blockIdx.x, t = threadIdx.x;
  float* r = out + (long)row * NVOCAB;
  float m = -1e30f, s = 0.0f;
  for (int k = t; k < NVOCAB; k += 256) {
    const float v = r[k];
    if (v > m) { s *= expf(m - v); m = v; }
    s += expf(v - m);
  }
  #pragma unroll
  for (int o = 32; o > 0; o >>= 1) {
    const float mo = __shfl_down(m, o, 64);
    const float so = __shfl_down(s, o, 64);
    const float M2 = fmaxf(m, mo);
    s = s * expf(m - M2) + so * expf(mo - M2);
    m = M2;
  }
  if ((t & 63) == 0) { rm[t >> 6] = m; rs[t >> 6] = s; }
  __syncthreads();
  const float M = fmaxf(fmaxf(rm[0], rm[1]), fmaxf(rm[2], rm[3]));
  const float S = rs[0] * expf(rm[0] - M) + rs[1] * expf(rm[1] - M) +
                  rs[2] * expf(rm[2] - M) + rs[3] * expf(rm[3] - M);
  const float inv = 1.0f / S;
  for (int k = t; k < NVOCAB; k += 256) r[k] = expf(r[k] - M) * inv;
}

// ---------------------------------------------------------------- launch
extern "C" void kernel_launch(void* const* d_in, const int* in_sizes, int n_in,
                              void* d_out, int out_size, void* d_ws, size_t ws_size,
                              hipStream_t stream) {
  (void)in_sizes; (void)n_in; (void)out_size; (void)ws_size;
  const int*   x_ids = (const int*)  d_in[0];
  const float* wemb  = (const float*)d_in[1];
  const float* pemb  = (const float*)d_in[2];
  const float* Wq    = (const float*)d_in[3];
  const float* bq    = (const float*)d_in[4];
  const float* Wk    = (const float*)d_in[5];
  const float* bk    = (const float*)d_in[6];
  const float* Wv    = (const float*)d_in[7];
  const float* bv    = (const float*)d_in[8];
  const float* Wo    = (const float*)d_in[9];
  const float* bo    = (const float*)d_in[10];
  const float* g1    = (const float*)d_in[11];
  const float* b1    = (const float*)d_in[12];
  const float* g2    = (const float*)d_in[13];
  const float* b2    = (const float*)d_in[14];
  const float* W1    = (const float*)d_in[15];
  const float* bm1   = (const float*)d_in[16];
  const float* W2    = (const float*)d_in[17];
  const float* bm2   = (const float*)d_in[18];
  const float* gf    = (const float*)d_in[19];
  const float* bfin  = (const float*)d_in[20];
  const float* Wu    = (const float*)d_in[21];
  const float* bu    = (const float*)d_in[22];

  char* ws = (char*)d_ws;                               // ~84.2 MiB of 1 GiB used
  float*  X    = (float*) ws;                           //  4 MiB fp32 residual
  bf16_t* ACT  = (bf16_t*)(ws + (4u  << 20));           //  2 MiB
  bf16_t* VbT  = (bf16_t*)(ws + (6u  << 20));           //  2 MiB  [h*64+v][seq]
  bf16_t* Ob   = (bf16_t*)(ws + (8u  << 20));           //  2 MiB  [h][q][v]
  bf16_t* Yb   = (bf16_t*)(ws + (10u << 20));           //  0.25 MiB [q][128]
  bf16_t* H1   = (bf16_t*)(ws + (12u << 20));           //  8 MiB
  bf16_t* QKb  = (bf16_t*)(ws + (20u << 20));           // 64 MiB [z=32][q][e] (Q heads 0-15, K heads 16-31)
  bf16_t* WuT  = (bf16_t*)(ws + (20u << 20));           // 62.5 MiB (QKb dead by final)
  float*  BIAS = (float*)(ws + (84u << 20));            // 128 KiB concat bq|bk

  bf16_t* Sb  = (bf16_t*)d_out;                         // 32 MiB scores/probs bf16 in-place
  bf16_t* WT  = (bf16_t*)((char*)d_out + (32u << 20));  // up to 64 MiB transposed bf16 weights
  float*  OUT = (float*)d_out;

  const long DD = (long)DEMB * DEMB;
  const long SD = (long)SEQ * DEMB;

  embed_k<<<SEQ, 256, 0, stream>>>(x_ids, wemb, pemb, X);

  for (int l = 0; l < NLAYER; ++l) {
    ln_k<<<SEQ, 256, 0, stream>>>(X, g1 + l * DEMB, b1 + l * DEMB, ACT, nullptr);

    // fused Q|K: transpose Wq[l],Wk[l] (32 head-matrices) then one 256^2 GEMM, z=32
    biascat_k<<<32, 256, 0, stream>>>(bq + (long)l * NHEAD * DEMB,
                                      bk + (long)l * NHEAD * DEMB, BIAS);
    tconv_k<<<dim3(32, 32, 32), 256, 0, stream>>>(
        Wq + (long)l * NHEAD * DD, Wk + (long)l * NHEAD * DD, NHEAD,
        WT, DEMB, DEMB, DD, DD);
    gemm256_k<0, false><<<dim3(4, 4, 32), 512, 0, stream>>>(
        ACT, WT, BIAS, QKb, SEQ, DEMB, DEMB, 0L, DD, SD, DEMB);

    // V (all heads fused, transposed store -> VbT[h*64+v][seq])
    tconv_k<<<dim3(2, 32, NHEAD), 256, 0, stream>>>(
        Wv + (long)l * DEMB * (NHEAD * DVDIM), nullptr, 0, WT, DEMB, DVDIM,
        (long)DEMB * DVDIM, (long)DVDIM * DEMB);
    gemm_k<4, 128, false, false><<<dim3(8, 8, 1), 256, 0, stream>>>(
        ACT, WT, bv + (long)l * NHEAD * DVDIM, VbT,
        SEQ, NHEAD * DVDIM, DEMB, 0L, 0L, 0L, 0);

    // scores S = Q @ K^T (256^2 8-phase, causal block skip)
    gemm256_k<0, true><<<dim3(4, 4, NHEAD), 512, 0, stream>>>(
        QKb, QKb + (long)NHEAD * SD, nullptr, Sb,
        SEQ, SEQ, DEMB, SD, SD, (long)SEQ * SEQ, 0);
    smax_k<<<dim3(SEQ, NHEAD), 256, 0, stream>>>(Sb);

    // O = P @ V
    gemm_k<0, 64, false, true><<<dim3(1, 8, NHEAD), 256, 0, stream>>>(
        Sb, VbT, nullptr, Ob,
        SEQ, DVDIM, SEQ, (long)SEQ * SEQ, (long)DVDIM * SEQ, (long)SEQ * DVDIM, 0);
    yasm_k<<<SEQ, 128, 0, stream>>>(Ob, Yb);

    // x += y @ Wo + bo (only first 128 rows of Wo live; K=128)
    tconv_k<<<dim3(32, 4, 1), 256, 0, stream>>>(
        Wo + (long)l * DD, nullptr, 0, WT, 128, DEMB, 0L, 0L);
    gemm_k<1, 128, false, false><<<dim3(8, 8, 1), 256, 0, stream>>>(
        Yb, WT, bo + (long)l * DEMB, X,
        SEQ, DEMB, 128, 0L, 0L, 0L, 0);

    ln_k<<<SEQ, 256, 0, stream>>>(X, g2 + l * DEMB, b2 + l * DEMB, ACT, X);

    // MLP
    tconv_k<<<dim3(128, 32, 1), 256, 0, stream>>>(
        W1 + (long)l * DEMB * DMLP, nullptr, 0, WT, DEMB, DMLP, 0L, 0L);
    gemm_k<3, 128, false, false><<<dim3(32, 8, 1), 256, 0, stream>>>(
        ACT, WT, bm1 + (long)l * DMLP, H1,
        SEQ, DMLP, DEMB, 0L, 0L, 0L, 0);
    tconv_k<<<dim3(32, 128, 1), 256, 0, stream>>>(
        W2 + (long)l * DMLP * DEMB, nullptr, 0, WT, DMLP, DEMB, 0L, 0L);
    gemm_k<1, 128, false, false><<<dim3(8, 8, 1), 256, 0, stream>>>(
        H1, WT, bm2 + (long)l * DEMB, X,
        SEQ, DEMB, DMLP, 0L, 0L, 0L, 0);
  }

  ln_k<<<SEQ, 256, 0, stream>>>(X, gf, bfin, ACT, nullptr);
  tconv_k<<<dim3(1000, 32, 1), 256, 0, stream>>>(Wu, nullptr, 0, WuT, DEMB, NVOCAB, 0L, 0L);
  gemm256_k<2, false><<<dim3(125, 4, 1), 512, 0, stream>>>(
      ACT, WuT, bu, OUT, SEQ, NVOCAB, DEMB, 0L, 0L, 0L, 0);
  vsmax_k<<<SEQ, 256, 0, stream>>>(OUT);
}

// Round 4
// 1507.070 us; speedup vs baseline: 3.1212x; 1.1550x over previous
//
#include <hip/hip_runtime.h>

typedef __bf16 bf16_t;
typedef __bf16 bf16x8 __attribute__((ext_vector_type(8)));
typedef float f32x4 __attribute__((ext_vector_type(4)));
typedef unsigned int u32;

#define SEQ    1024
#define DEMB   1024
#define NHEAD  16
#define DVDIM  64
#define DMLP   4096
#define NVOCAB 32000
#define NLAYER 4

typedef const __attribute__((address_space(1))) void gas_t;
typedef __attribute__((address_space(3))) void las_t;

__device__ __forceinline__ void gload_lds16(const void* g, void* l) {
  __builtin_amdgcn_global_load_lds((gas_t*)g, (las_t*)l, 16, 0, 0);
}

union PackU { bf16_t h[2]; u32 u; };
union B4U  { uint2 u; bf16_t h[4]; };

// ---------------------------------------------------------------- reductions
__device__ __forceinline__ float blockSum(float v, float* red) {
  #pragma unroll
  for (int o = 32; o > 0; o >>= 1) v += __shfl_down(v, o, 64);
  __syncthreads();
  if ((threadIdx.x & 63) == 0) red[threadIdx.x >> 6] = v;
  __syncthreads();
  return (red[0] + red[1]) + (red[2] + red[3]);
}
__device__ __forceinline__ float blockMax(float v, float* red) {
  #pragma unroll
  for (int o = 32; o > 0; o >>= 1) v = fmaxf(v, __shfl_down(v, o, 64));
  __syncthreads();
  if ((threadIdx.x & 63) == 0) red[threadIdx.x >> 6] = v;
  __syncthreads();
  return fmaxf(fmaxf(red[0], red[1]), fmaxf(red[2], red[3]));
}

// ---------------------------------------------------------------- embed
__global__ void embed_k(const int* __restrict__ ids, const float* __restrict__ we,
                        const float* __restrict__ pe, float* __restrict__ x) {
  const int row = blockIdx.x, t = threadIdx.x;
  const long id = ids[row];
  float4 a = *(const float4*)(we + id * (long)DEMB + t * 4);
  float4 b = *(const float4*)(pe + (long)row * DEMB + t * 4);
  float4 o; o.x = a.x + b.x; o.y = a.y + b.y; o.z = a.z + b.z; o.w = a.w + b.w;
  *(float4*)(x + (long)row * DEMB + t * 4) = o;
}

// ---------------------------------------------------------------- layernorm
__global__ void __launch_bounds__(256)
ln_k(const float* __restrict__ x, const float* __restrict__ g,
     const float* __restrict__ b, bf16_t* __restrict__ xn,
     float* __restrict__ xupd) {
  __shared__ float red[4];
  const int row = blockIdx.x, t = threadIdx.x;
  const float* xr = x + (long)row * DEMB;
  float4 v = *(const float4*)(xr + t * 4);
  float mu = blockSum(v.x + v.y + v.z + v.w, red) * (1.0f / DEMB);
  float dx = v.x - mu, dy = v.y - mu, dz = v.z - mu, dw = v.w - mu;
  float var = blockSum(dx * dx + dy * dy + dz * dz + dw * dw, red) * (1.0f / DEMB);
  float inv = 1.0f / sqrtf(var);
  float4 gv = *(const float4*)(g + t * 4);
  float4 bv = *(const float4*)(b + t * 4);
  float o0 = gv.x * dx * inv + bv.x;
  float o1 = gv.y * dy * inv + bv.y;
  float o2 = gv.z * dz * inv + bv.z;
  float o3 = gv.w * dw * inv + bv.w;
  PackU p0, p1;
  p0.h[0] = (bf16_t)o0; p0.h[1] = (bf16_t)o1;
  p1.h[0] = (bf16_t)o2; p1.h[1] = (bf16_t)o3;
  uint2 st; st.x = p0.u; st.y = p1.u;
  *(uint2*)(xn + (long)row * DEMB + t * 4) = st;
  if (xupd) {
    float4 nv; nv.x = v.x + o0; nv.y = v.y + o1; nv.z = v.z + o2; nv.w = v.w + o3;
    *(float4*)(xupd + (long)row * DEMB + t * 4) = nv;
  }
}

// ---------------------------------------------------------------- all-layer bias concat (bq|bk) -> BIAS[128][DEMB]
__global__ void biascat_k(const float* __restrict__ bq, const float* __restrict__ bk,
                          float* __restrict__ out) {
  const int z = blockIdx.x, t = threadIdx.x;     // z = l*32 + i
  const int l = z >> 5, i = z & 31;
  const float* src = (i < NHEAD) ? (bq + (long)(l * NHEAD + i) * DEMB)
                                 : (bk + (long)(l * NHEAD + i - NHEAD) * DEMB);
  *(float4*)(out + (long)z * DEMB + t * 4) = *(const float4*)(src + t * 4);
}

// ---------------------------------------------------------------- zero Yb (once; cols 79..127 stay 0 all layers)
__global__ void zyb_k(bf16_t* __restrict__ y) {
  *(uint4*)((char*)y + ((long)blockIdx.x * 256 + threadIdx.x) * 16) = uint4{0, 0, 0, 0};
}

// ---------------------------------------------------------------- transpose-convert fp32 (R x C) -> bf16 (C x R)
// 64x64 tiles, float2 loads, uint4 (8 bf16) stores, both fully coalesced.
// QK mode: z = l*32+i, i<16 -> in (Wq, head l*16+i), else in2 (Wk).
template<bool QK>
__global__ void __launch_bounds__(256)
tconv2_k(const float* __restrict__ in, const float* __restrict__ in2,
         bf16_t* __restrict__ out, int R, int C, long inB, long outB) {
  __shared__ bf16_t tl[64][72];
  const int z = blockIdx.z;
  const float* ip;
  if (QK) {
    const int l = z >> 5, i = z & 31;
    ip = (i < NHEAD) ? (in + (long)(l * NHEAD + i) * inB)
                     : (in2 + (long)(l * NHEAD + i - NHEAD) * inB);
  } else {
    ip = in + (long)z * inB;
  }
  bf16_t* op = out + (long)z * outB;
  const int c0 = blockIdx.x * 64, r0 = blockIdx.y * 64;
  const int t = threadIdx.x;
  const int cc = (t & 31) * 2, rr = t >> 5;
  #pragma unroll
  for (int p = 0; p < 8; ++p) {
    const int r = rr + p * 8;
    float2 v = *(const float2*)(ip + (long)(r0 + r) * C + (c0 + cc));
    tl[cc][r]     = (bf16_t)v.x;
    tl[cc + 1][r] = (bf16_t)v.y;
  }
  __syncthreads();
  const int oc = t >> 2, rk = (t & 3) * 16;
  uint4 a = *(const uint4*)&tl[oc][rk];
  uint4 b = *(const uint4*)&tl[oc][rk + 8];
  *(uint4*)(op + (long)(c0 + oc) * R + (r0 + rk))     = a;
  *(uint4*)(op + (long)(c0 + oc) * R + (r0 + rk + 8)) = b;
}

// ---------------------------------------------------------------- 128x128 GEMM (m97 structure)
// C[m][n] = sum_k A[m][k]*B[n][k] (+bias). lda/ldb = row strides.
// MODE: 0 bf16, 1 fp32 +=, 2 fp32, 3 gelu->bf16, 4 bf16 transposed, 6 diag-pack Yb.
template<int MODE, int BN, bool CAUSAL, bool TRIMK>
__global__ void __launch_bounds__(256)
gemm_k(const bf16_t* __restrict__ A, const bf16_t* __restrict__ B,
       const float* __restrict__ bias, void* __restrict__ Cv,
       int M, int N, int K, int lda, int ldb,
       long aB, long bB, long cB, int biasB) {
  __shared__ bf16_t lsA[128 * 32];
  __shared__ bf16_t lsB[BN * 32];

  const int t = threadIdx.x;
  const int bz = blockIdx.z;
  const int m0 = blockIdx.y * 128;
  const int n0 = blockIdx.x * BN;
  if (CAUSAL && n0 > m0 + 127) return;

  const bf16_t* Ap = A + (long)bz * aB;
  const bf16_t* Bp = B + (long)bz * bB;
  const int kEnd = TRIMK ? min(K, m0 + 128) : K;

  constexpr int NS = BN / 32;
  const int lane = t & 63;
  const int wid = t >> 6;
  const int wr = (wid >> 1) * 64;
  const int wc = (wid & 1) * (BN / 2);
  const int fr = lane & 15, fg = lane >> 4;
  const int srow = lane >> 2;
  const int skc  = (lane & 3) * 8;

  f32x4 acc[4][NS] = {};

  for (int k0 = 0; k0 < kEnd; k0 += 32) {
    if (k0) __syncthreads();
    #pragma unroll
    for (int i = 0; i < 2; ++i) {
      const int seg = wid * 2 + i;
      gload_lds16(Ap + (long)(m0 + seg * 16 + srow) * lda + (k0 + skc),
                  lsA + seg * 512);
    }
    if (BN == 128) {
      #pragma unroll
      for (int i = 0; i < 2; ++i) {
        const int seg = wid * 2 + i;
        gload_lds16(Bp + (long)(n0 + seg * 16 + srow) * ldb + (k0 + skc),
                    lsB + seg * 512);
      }
    } else {
      gload_lds16(Bp + (long)(n0 + wid * 16 + srow) * ldb + (k0 + skc),
                  lsB + wid * 512);
    }
    __syncthreads();

    bf16x8 af[4], bfv[NS];
    #pragma unroll
    for (int ms = 0; ms < 4; ++ms)
      af[ms] = *(const bf16x8*)(lsA + (wr + ms * 16 + fr) * 32 + fg * 8);
    #pragma unroll
    for (int ns = 0; ns < NS; ++ns)
      bfv[ns] = *(const bf16x8*)(lsB + (wc + ns * 16 + fr) * 32 + fg * 8);
    #pragma unroll
    for (int ms = 0; ms < 4; ++ms)
      #pragma unroll
      for (int ns = 0; ns < NS; ++ns)
        acc[ms][ns] = __builtin_amdgcn_mfma_f32_16x16x32_bf16(
            af[ms], bfv[ns], acc[ms][ns], 0, 0, 0);
  }

  #pragma unroll
  for (int ms = 0; ms < 4; ++ms) {
    #pragma unroll
    for (int ns = 0; ns < NS; ++ns) {
      const int col = n0 + wc + ns * 16 + fr;
      const float bvv = bias ? bias[(long)bz * biasB + col] : 0.0f;
      #pragma unroll
      for (int r = 0; r < 4; ++r) {
        const int row = m0 + wr + ms * 16 + fg * 4 + r;
        float v = acc[ms][ns][r] + bvv;
        if (MODE == 0) {
          ((bf16_t*)Cv)[(long)bz * cB + (long)row * N + col] = (bf16_t)v;
        } else if (MODE == 1) {
          ((float*)Cv)[(long)bz * cB + (long)row * N + col] += v;
        } else if (MODE == 2) {
          ((float*)Cv)[(long)bz * cB + (long)row * N + col] = v;
        } else if (MODE == 3) {
          float gl = 0.5f * v * (1.0f + tanhf(0.7978845608028654f * (v + 0.044715f * v * v * v)));
          ((bf16_t*)Cv)[(long)bz * cB + (long)row * N + col] = (bf16_t)gl;
        } else if (MODE == 4) {
          ((bf16_t*)Cv)[(long)col * M + row] = (bf16_t)v;
        } else {   // MODE 6: overlapping-slice y assembly, Cv = Yb[1024][128], bz = head
          if (bz == NHEAD - 1) {
            ((bf16_t*)Cv)[(long)row * 128 + (NHEAD - 1) + col] = (bf16_t)v;
          } else if (col == 0) {
            ((bf16_t*)Cv)[(long)row * 128 + bz] = (bf16_t)v;
          }
        }
      }
    }
  }
}

// ---------------------------------------------------------------- 256x256 8-phase GEMM (m201 template)
#define GPHASE(buf, mh, nh, STAGE, VM) do {                                            \
  bf16x8 af[4][2], bfv[2][2];                                                          \
  _Pragma("unroll") for (int mf = 0; mf < 4; ++mf) {                                   \
    const int r = wm * 128 + ((mh) * 4 + mf) * 16 + (lane & 15);                       \
    _Pragma("unroll") for (int ks = 0; ks < 2; ++ks) {                                 \
      const int slot = ks * 4 + (lane >> 4);                                           \
      af[mf][ks] = *(const bf16x8*)(lds + (buf) * 32768 + r * 64 +                     \
                                    ((slot ^ (r & 7)) << 3)); } }                      \
  _Pragma("unroll") for (int nf = 0; nf < 2; ++nf) {                                   \
    const int r = wn * 64 + ((nh) * 2 + nf) * 16 + (lane & 15);                        \
    _Pragma("unroll") for (int ks = 0; ks < 2; ++ks) {                                 \
      const int slot = ks * 4 + (lane >> 4);                                           \
      bfv[nf][ks] = *(const bf16x8*)(lds + (buf) * 32768 + 16384 + r * 64 +            \
                                     ((slot ^ (r & 7)) << 3)); } }                     \
  STAGE;                                                                               \
  __builtin_amdgcn_s_barrier();                                                        \
  asm volatile("s_waitcnt lgkmcnt(0)" ::: "memory");                                   \
  __builtin_amdgcn_sched_barrier(0);                                                   \
  __builtin_amdgcn_s_setprio(1);                                                       \
  _Pragma("unroll") for (int mf = 0; mf < 4; ++mf)                                     \
    _Pragma("unroll") for (int nf = 0; nf < 2; ++nf)                                   \
      _Pragma("unroll") for (int ks = 0; ks < 2; ++ks)                                 \
        acc[(mh) * 4 + mf][(nh) * 2 + nf] = __builtin_amdgcn_mfma_f32_16x16x32_bf16(   \
            af[mf][ks], bfv[nf][ks], acc[(mh) * 4 + mf][(nh) * 2 + nf], 0, 0, 0);      \
  __builtin_amdgcn_s_setprio(0);                                                       \
  VM;                                                                                  \
  __builtin_amdgcn_s_barrier();                                                        \
} while (0)

template<int MODE, bool CAUSAL>
__global__ void __launch_bounds__(512, 1)
gemm256_k(const bf16_t* __restrict__ A, const bf16_t* __restrict__ B,
          const float* __restrict__ bias, void* __restrict__ Cv,
          int M, int N, int K, long aB, long bB, long cB, int biasB) {
  __shared__ bf16_t lds[65536];

  const int t = threadIdx.x;
  const int lane = t & 63, w = t >> 6;
  const int wm = w >> 2, wn = w & 3;
  const int bz = blockIdx.z;
  const int m0 = blockIdx.y * 256, n0 = blockIdx.x * 256;
  if (CAUSAL && n0 > m0 + 255) return;

  const bf16_t* Ap = A + (long)bz * aB;
  const bf16_t* Bp = B + (long)bz * bB;
  const int NT = K >> 6;

  f32x4 acc[8][4] = {};

  auto stA = [&](int half, int kt, int buf) {
    #pragma unroll
    for (int rr = 0; rr < 2; ++rr) {
      const int rw0 = rr * 64 + w * 8;
      const int row0 = ((rw0 >> 6) << 7) | (half << 6) | (rw0 & 63);
      const int r = row0 + (lane >> 3);
      const int slot = lane & 7;
      gload_lds16(Ap + (long)(m0 + r) * K + (kt << 6) + ((slot ^ (r & 7)) << 3),
                  lds + buf * 32768 + row0 * 64);
    }
  };
  auto stB = [&](int half, int kt, int buf) {
    #pragma unroll
    for (int rr = 0; rr < 2; ++rr) {
      const int rw0 = rr * 64 + w * 8;
      const int row0 = ((rw0 >> 5) << 6) | (half << 5) | (rw0 & 31);
      const int r = row0 + (lane >> 3);
      const int slot = lane & 7;
      gload_lds16(Bp + (long)(n0 + r) * K + (kt << 6) + ((slot ^ (r & 7)) << 3),
                  lds + buf * 32768 + 16384 + row0 * 64);
    }
  };

  stB(0, 0, 0); stA(0, 0, 0); stA(1, 0, 0); stB(1, 0, 0);
  stB(0, 1, 1); stA(0, 1, 1);
  asm volatile("s_waitcnt vmcnt(4)" ::: "memory");
  __builtin_amdgcn_s_barrier();

  for (int it = 0; it < (NT >> 1); ++it) {
    const int tt = it * 2;
    const int s1 = min(tt + 1, NT - 1);
    const int s2 = min(tt + 2, NT - 1);
    const int s3 = min(tt + 3, NT - 1);
    GPHASE(0, 0, 0, { stA(1, s1, 1); }, );
    GPHASE(0, 1, 0, { stB(1, s1, 1); }, );
    GPHASE(0, 0, 1, { stB(0, s2, 0); }, );
    GPHASE(0, 1, 1, { stA(0, s2, 0); }, asm volatile("s_waitcnt vmcnt(4)" ::: "memory"));
    GPHASE(1, 0, 0, { stA(1, s2, 0); }, );
    GPHASE(1, 1, 0, { stB(1, s2, 0); }, );
    GPHASE(1, 0, 1, { stB(0, s3, 1); }, );
    GPHASE(1, 1, 1, { stA(0, s3, 1); }, asm volatile("s_waitcnt vmcnt(4)" ::: "memory"));
  }
  asm volatile("s_waitcnt vmcnt(0)" ::: "memory");

  #pragma unroll
  for (int mf = 0; mf < 8; ++mf) {
    #pragma unroll
    for (int nf = 0; nf < 4; ++nf) {
      const int col = n0 + wn * 64 + nf * 16 + (lane & 15);
      const float bvv = bias ? bias[(long)bz * biasB + col] : 0.0f;
      #pragma unroll
      for (int r = 0; r < 4; ++r) {
        const int row = m0 + wm * 128 + mf * 16 + (lane >> 4) * 4 + r;
        const float v = acc[mf][nf][r] + bvv;
        if (MODE == 0)
          ((bf16_t*)Cv)[(long)bz * cB + (long)row * N + col] = (bf16_t)v;
        else
          ((float*)Cv)[(long)bz * cB + (long)row * N + col] = v;
      }
    }
  }
}

// ---------------------------------------------------------------- causal softmax, in-place on bf16 scores
__global__ void __launch_bounds__(256)
smax_k(bf16_t* __restrict__ s) {
  __shared__ float red[4];
  const int q = blockIdx.x, h = blockIdx.y, t = threadIdx.x;
  bf16_t* sr = s + ((long)h * SEQ + q) * SEQ;
  const int L = q + 1;
  const float scale = 0.03125f;
  B4U b; b.u = *(const uint2*)(sr + t * 4);
  float x[4];
  float m = -1e30f;
  #pragma unroll
  for (int j = 0; j < 4; ++j) {
    x[j] = (float)b.h[j] * scale;
    if (t * 4 + j < L) m = fmaxf(m, x[j]);
  }
  m = blockMax(m, red);
  float e[4], sum = 0.0f;
  #pragma unroll
  for (int j = 0; j < 4; ++j) {
    e[j] = (t * 4 + j < L) ? expf(x[j] - m) : 0.0f;
    sum += e[j];
  }
  __syncthreads();
  sum = blockSum(sum, red);
  const float inv = 1.0f / sum;
  #pragma unroll
  for (int j = 0; j < 4; ++j) b.h[j] = (bf16_t)(e[j] * inv);
  *(uint2*)(sr + t * 4) = b.u;
}

// ---------------------------------------------------------------- MLP2 split-K reduce: X += sum(P[0..3]) + bm2
__global__ void __launch_bounds__(256)
reduce_k(const float* __restrict__ P, const float* __restrict__ bm2,
         float* __restrict__ X) {
  const long i = (long)blockIdx.x * 1024 + threadIdx.x * 4;
  float4 x = *(float4*)(X + i);
  #pragma unroll
  for (int z = 0; z < 4; ++z) {
    float4 p = *(const float4*)(P + (long)z * 1048576 + i);
    x.x += p.x; x.y += p.y; x.z += p.z; x.w += p.w;
  }
  float4 b = *(const float4*)(bm2 + threadIdx.x * 4);
  x.x += b.x; x.y += b.y; x.z += b.z; x.w += b.w;
  *(float4*)(X + i) = x;
}

// ---------------------------------------------------------------- final vocab softmax, single read+write
__global__ void __launch_bounds__(1024)
vsmax_k(float* __restrict__ out) {
  __shared__ float rm[16], rs[16];
  const int row = blockIdx.x, t = threadIdx.x;
  float* r = out + (long)row * NVOCAB;
  float v[32];
  const int nlast = (t < NVOCAB - 31 * 1024) ? 32 : 31;   // j=31 valid only t<256
  float m = -1e30f;
  #pragma unroll
  for (int j = 0; j < 31; ++j) { v[j] = r[j * 1024 + t]; m = fmaxf(m, v[j]); }
  if (nlast == 32) { v[31] = r[31 * 1024 + t]; m = fmaxf(m, v[31]); } else v[31] = -1e30f;
  float s = 0.0f;
  #pragma unroll
  for (int j = 0; j < 32; ++j) s += expf(v[j] - m);   // invalid -> exp(-huge)=0
  #pragma unroll
  for (int o = 32; o > 0; o >>= 1) {
    const float mo = __shfl_down(m, o, 64);
    const float so = __shfl_down(s, o, 64);
    const float M2 = fmaxf(m, mo);
    s = s * expf(m - M2) + so * expf(mo - M2);
    m = M2;
  }
  if ((t & 63) == 0) { rm[t >> 6] = m; rs[t >> 6] = s; }
  __syncthreads();
  float M = -1e30f;
  #pragma unroll
  for (int i = 0; i < 16; ++i) M = fmaxf(M, rm[i]);
  float S = 0.0f;
  #pragma unroll
  for (int i = 0; i < 16; ++i) S += rs[i] * expf(rm[i] - M);
  const float inv = 1.0f / S;
  #pragma unroll
  for (int j = 0; j < 31; ++j) r[j * 1024 + t] = expf(v[j] - M) * inv;
  if (nlast == 32) r[31 * 1024 + t] = expf(v[31] - M) * inv;
}

// ---------------------------------------------------------------- launch
extern "C" void kernel_launch(void* const* d_in, const int* in_sizes, int n_in,
                              void* d_out, int out_size, void* d_ws, size_t ws_size,
                              hipStream_t stream) {
  (void)in_sizes; (void)n_in; (void)out_size; (void)ws_size;
  const int*   x_ids = (const int*)  d_in[0];
  const float* wemb  = (const float*)d_in[1];
  const float* pemb  = (const float*)d_in[2];
  const float* Wq    = (const float*)d_in[3];
  const float* bq    = (const float*)d_in[4];
  const float* Wk    = (const float*)d_in[5];
  const float* bk    = (const float*)d_in[6];
  const float* Wv    = (const float*)d_in[7];
  const float* bv    = (const float*)d_in[8];
  const float* Wo    = (const float*)d_in[9];
  const float* bo    = (const float*)d_in[10];
  const float* g1    = (const float*)d_in[11];
  const float* b1    = (const float*)d_in[12];
  const float* g2    = (const float*)d_in[13];
  const float* b2    = (const float*)d_in[14];
  const float* W1    = (const float*)d_in[15];
  const float* bm1   = (const float*)d_in[16];
  const float* W2    = (const float*)d_in[17];
  const float* bm2   = (const float*)d_in[18];
  const float* gf    = (const float*)d_in[19];
  const float* bfin  = (const float*)d_in[20];
  const float* Wu    = (const float*)d_in[21];
  const float* bu    = (const float*)d_in[22];

  char* ws = (char*)d_ws;                               // ~527 MiB of 1 GiB used
  float*  X    = (float*) ws;                           //   0- 4  fp32 residual
  bf16_t* ACT  = (bf16_t*)(ws + (4u   << 20));          //   4- 6
  bf16_t* VbT  = (bf16_t*)(ws + (6u   << 20));          //   6- 8  [h*64+v][seq]
  bf16_t* Yb   = (bf16_t*)(ws + (10u  << 20));          //  10-10.25 [q][128]
  bf16_t* H1   = (bf16_t*)(ws + (12u  << 20));          //  12-20
  bf16_t* QKb  = (bf16_t*)(ws + (20u  << 20));          //  20-84 [z=32][q][e]
  float*  PART = (float*) (ws + (84u  << 20));          //  84-100 MLP2 split-K
  float*  BIAS = (float*) (ws + (100u << 20));          // 100-100.5 [l*32+i][e]
  bf16_t* WTqk = (bf16_t*)(ws + (128u << 20));          // 128-384 [l*32+i][e][d]
  bf16_t* WTv  = (bf16_t*)(ws + (384u << 20));          // 384-392 [l*16+h][v][d]
  bf16_t* WTo  = (bf16_t*)(ws + (392u << 20));          // 392-393 [l][e][128]
  bf16_t* WT1  = (bf16_t*)(ws + (400u << 20));          // 400-432 [l][dm][d]
  bf16_t* WT2  = (bf16_t*)(ws + (432u << 20));          // 432-464 [l][d][dm]
  bf16_t* WTu  = (bf16_t*)(ws + (464u << 20));          // 464-526.5 [v][d]

  bf16_t* Sb  = (bf16_t*)d_out;                         // 32 MiB scores/probs
  float*  OUT = (float*)d_out;

  const long DD = (long)DEMB * DEMB;
  const long SD = (long)SEQ * DEMB;

  // ---------------- prologue: embed + all weight prep (input-only dependent)
  embed_k<<<SEQ, 256, 0, stream>>>(x_ids, wemb, pemb, X);
  biascat_k<<<128, 256, 0, stream>>>(bq, bk, BIAS);
  zyb_k<<<64, 256, 0, stream>>>(Yb);
  tconv2_k<true><<<dim3(16, 16, 128), 256, 0, stream>>>(Wq, Wk, WTqk, DEMB, DEMB, DD, DD);
  tconv2_k<false><<<dim3(1, 16, 64), 256, 0, stream>>>(
      Wv, nullptr, WTv, DEMB, DVDIM, (long)DEMB * DVDIM, (long)DVDIM * DEMB);
  tconv2_k<false><<<dim3(16, 2, 4), 256, 0, stream>>>(
      Wo, nullptr, WTo, 128, DEMB, DD, (long)DEMB * 128);
  tconv2_k<false><<<dim3(64, 16, 4), 256, 0, stream>>>(
      W1, nullptr, WT1, DEMB, DMLP, (long)DEMB * DMLP, (long)DMLP * DEMB);
  tconv2_k<false><<<dim3(16, 64, 4), 256, 0, stream>>>(
      W2, nullptr, WT2, DMLP, DEMB, (long)DMLP * DEMB, (long)DEMB * DMLP);
  tconv2_k<false><<<dim3(500, 16, 1), 256, 0, stream>>>(
      Wu, nullptr, WTu, DEMB, NVOCAB, 0L, 0L);

  for (int l = 0; l < NLAYER; ++l) {
    ln_k<<<SEQ, 256, 0, stream>>>(X, g1 + l * DEMB, b1 + l * DEMB, ACT, nullptr);

    // fused Q|K projection: one 256^2 GEMM, z = 32 heads
    gemm256_k<0, false><<<dim3(4, 4, 32), 512, 0, stream>>>(
        ACT, WTqk + (long)l * 32 * DD, BIAS + (long)l * 32 * DEMB, QKb,
        SEQ, DEMB, DEMB, 0L, DD, SD, DEMB);

    // V projection (all heads fused, transposed store -> VbT)
    gemm_k<4, 128, false, false><<<dim3(8, 8, 1), 256, 0, stream>>>(
        ACT, WTv + (long)l * DD, bv + (long)l * NHEAD * DVDIM, VbT,
        SEQ, NHEAD * DVDIM, DEMB, DEMB, DEMB, 0L, 0L, 0L, 0);

    // scores S = Q @ K^T (causal block skip)
    gemm256_k<0, true><<<dim3(4, 4, NHEAD), 512, 0, stream>>>(
        QKb, QKb + (long)NHEAD * SD, nullptr, Sb,
        SEQ, SEQ, DEMB, SD, SD, (long)SEQ * SEQ, 0);
    smax_k<<<dim3(SEQ, NHEAD), 256, 0, stream>>>(Sb);

    // O = P @ V with fused overlapping-slice y assembly (MODE 6 -> Yb)
    gemm_k<6, 64, false, true><<<dim3(1, 8, NHEAD), 256, 0, stream>>>(
        Sb, VbT, nullptr, Yb,
        SEQ, DVDIM, SEQ, SEQ, SEQ, (long)SEQ * SEQ, (long)DVDIM * SEQ, 0L, 0);

    // x += y @ Wo + bo (K=128: only first 128 Wo rows live)
    gemm_k<1, 128, false, false><<<dim3(8, 8, 1), 256, 0, stream>>>(
        Yb, WTo + (long)l * DEMB * 128, bo + (long)l * DEMB, X,
        SEQ, DEMB, 128, 128, 128, 0L, 0L, 0L, 0);

    ln_k<<<SEQ, 256, 0, stream>>>(X, g2 + l * DEMB, b2 + l * DEMB, ACT, X);

    // MLP1: gelu(xn2 @ W1 + bm1)
    gemm_k<3, 128, false, false><<<dim3(32, 8, 1), 256, 0, stream>>>(
        ACT, WT1 + (long)l * DMLP * DEMB, bm1 + (long)l * DMLP, H1,
        SEQ, DMLP, DEMB, DEMB, DEMB, 0L, 0L, 0L, 0);
    // MLP2 split-K (z = 4 K-chunks of 1024) -> PART, then reduce into X
    gemm_k<2, 128, false, false><<<dim3(8, 8, 4), 256, 0, stream>>>(
        H1, WT2 + (long)l * DEMB * DMLP, nullptr, PART,
        SEQ, DEMB, 1024, DMLP, DMLP, 1024L, 1024L, (long)SEQ * DEMB, 0);
    reduce_k<<<SEQ, 256, 0, stream>>>(PART, bm2 + (long)l * DEMB, X);
  }

  ln_k<<<SEQ, 256, 0, stream>>>(X, gf, bfin, ACT, nullptr);
  gemm256_k<2, false><<<dim3(125, 4, 1), 512, 0, stream>>>(
      ACT, WTu, bu, OUT, SEQ, NVOCAB, DEMB, 0L, 0L, 0L, 0);
  vsmax_k<<<SEQ, 1024, 0, stream>>>(OUT);
}